// Round 1
// baseline (86.334 us; speedup 1.0000x reference)
//
#include <hip/hip_runtime.h>

// Problem constants (fixed by setup_inputs): N=512 anchors, D=128 dims, K=16 co-occurrence width.
constexpr int NN = 512;
constexpr int DD = 128;
constexpr int KK = 16;
#define ALPHA 0.1f

__global__ void zero_kernel(float* out) {
    if (threadIdx.x == 0) out[0] = 0.0f;
}

// One block per anchor i. 256 threads.
__global__ __launch_bounds__(256) void area_loss_kernel(
    const float* __restrict__ wid,
    const float* __restrict__ ken,
    const float* __restrict__ lrg,
    const float* __restrict__ sml,
    const float* __restrict__ yad,
    const int*   __restrict__ x,
    float* __restrict__ out)
{
    __shared__ float    yi[DD];          // yad[i]
    __shared__ float    d2[NN];          // ||yad_i - yad_j||^2 for all j
    __shared__ unsigned mask[NN / 32];   // membership bitset: j in x[i]
    __shared__ float    posd[KK];        // d2 of pos-set (<=16 distinct)
    __shared__ int      pcnt;
    __shared__ float    wsum[4];

    const int i = blockIdx.x;
    const int t = threadIdx.x;

    // Stage yad_i + init shared state.
    if (t < DD)      yi[t]   = yad[(size_t)i * DD + t];
    if (t < NN / 32) mask[t] = 0u;
    if (t == 0)      pcnt    = 0;
    __syncthreads();

    // Build membership bitmask from x[i][0..K). Duplicates collapse (matches
    // the reference's scatter-to-bool-mask semantics).
    if (t < KK) {
        int j = x[i * KK + t];
        atomicOr(&mask[j >> 5], 1u << (j & 31));
    }

    // Pairwise squared distances: d2[j] = sum_d (yad_i[d] - yad_j[d])^2.
    // Each thread handles j = t and j = t + 256. float4 loads; yi reads are
    // same-address broadcasts (bank-conflict free).
    for (int j = t; j < NN; j += 256) {
        const float4* row = (const float4*)(yad + (size_t)j * DD);
        float acc = 0.f;
#pragma unroll
        for (int c = 0; c < DD / 4; ++c) {
            float4 v = row[c];
            float e0 = v.x - yi[4 * c + 0];
            float e1 = v.y - yi[4 * c + 1];
            float e2 = v.z - yi[4 * c + 2];
            float e3 = v.w - yi[4 * c + 3];
            acc += e0 * e0 + e1 * e1 + e2 * e2 + e3 * e3;
        }
        d2[j] = acc;
    }
    __syncthreads();

    // Gather pos-set distances (j in x[i], j != i): at most K entries.
    for (int j = t; j < NN; j += 256) {
        if (j != i && ((mask[j >> 5] >> (j & 31)) & 1u)) {
            int p = atomicAdd(&pcnt, 1);
            posd[p] = d2[j];
        }
    }
    __syncthreads();

    const int P = pcnt;
    float acc = 0.f;

    // Triplet hinge: sum over k in neg-set, j in pos-set of
    // relu(d2[j] - d2[k] + alpha).
    for (int k = t; k < NN; k += 256) {
        if (k != i && !((mask[k >> 5] >> (k & 31)) & 1u)) {
            float dk = d2[k];
            for (int p = 0; p < P; ++p) {
                acc += fmaxf(posd[p] - dk + ALPHA, 0.f);
            }
        }
    }

    // Fused hierarchical consistency term for row i (threads 0..127 cover D).
    if (t < DD) {
        size_t idx = (size_t)i * DD + t;
        float w = wid[idx], kk = ken[idx], l = lrg[idx], s = sml[idx], y = yi[t];
        float a = w - kk, b = w - l, c = l - s, e = s - y;
        acc += a * a + b * b + c * c + e * e;
    }

    // Block reduction: shuffle within each 64-lane wave, then LDS across 4 waves.
    for (int off = 32; off; off >>= 1) acc += __shfl_down(acc, off, 64);
    if ((t & 63) == 0) wsum[t >> 6] = acc;
    __syncthreads();
    if (t == 0) {
        atomicAdd(out, wsum[0] + wsum[1] + wsum[2] + wsum[3]);
    }
}

extern "C" void kernel_launch(void* const* d_in, const int* in_sizes, int n_in,
                              void* d_out, int out_size, void* d_ws, size_t ws_size,
                              hipStream_t stream) {
    const float* wid = (const float*)d_in[0];
    const float* ken = (const float*)d_in[1];
    const float* lrg = (const float*)d_in[2];
    const float* sml = (const float*)d_in[3];
    const float* yad = (const float*)d_in[4];
    const int*   x   = (const int*)d_in[5];
    float* out = (float*)d_out;

    zero_kernel<<<1, 64, 0, stream>>>(out);
    area_loss_kernel<<<NN, 256, 0, stream>>>(wid, ken, lrg, sml, yad, x, out);
}

// Round 2
// 82.191 us; speedup vs baseline: 1.0504x; 1.0504x over previous
//
#include <hip/hip_runtime.h>

// Problem constants (fixed by setup_inputs): N=512 anchors, D=128 dims, K=16 co-occurrence width.
constexpr int NN = 512;
constexpr int DD = 128;
constexpr int KK = 16;
#define ALPHA 0.1f

// One block per anchor i. 256 threads. Writes per-anchor partial loss to
// partial[i] -- no global atomics (cross-XCD atomic serialization to a single
// address was the suspected 86us bottleneck).
__global__ __launch_bounds__(256) void area_loss_kernel(
    const float* __restrict__ wid,
    const float* __restrict__ ken,
    const float* __restrict__ lrg,
    const float* __restrict__ sml,
    const float* __restrict__ yad,
    const int*   __restrict__ x,
    float* __restrict__ partial)
{
    __shared__ float    yi[DD];          // yad[i]
    __shared__ float    d2[NN];          // ||yad_i - yad_j||^2 for all j
    __shared__ unsigned mask[NN / 32];   // membership bitset: j in x[i]
    __shared__ float    posd[KK];        // d2 of pos-set (<=16 distinct)
    __shared__ int      pcnt;
    __shared__ float    wsum[4];

    const int i = blockIdx.x;
    const int t = threadIdx.x;

    // Stage yad_i + init shared state.
    if (t < DD)      yi[t]   = yad[(size_t)i * DD + t];
    if (t < NN / 32) mask[t] = 0u;
    if (t == 0)      pcnt    = 0;
    __syncthreads();

    // Build membership bitmask from x[i][0..K). Duplicates collapse (matches
    // the reference's scatter-to-bool-mask semantics).
    if (t < KK) {
        int j = x[i * KK + t];
        atomicOr(&mask[j >> 5], 1u << (j & 31));
    }

    // Pairwise squared distances: d2[j] = sum_d (yad_i[d] - yad_j[d])^2.
    // Each thread handles j = t and j = t + 256. float4 loads (L2-resident);
    // yi reads are same-address broadcasts (bank-conflict free).
    for (int j = t; j < NN; j += 256) {
        const float4* row = (const float4*)(yad + (size_t)j * DD);
        float acc = 0.f;
#pragma unroll
        for (int c = 0; c < DD / 4; ++c) {
            float4 v = row[c];
            float e0 = v.x - yi[4 * c + 0];
            float e1 = v.y - yi[4 * c + 1];
            float e2 = v.z - yi[4 * c + 2];
            float e3 = v.w - yi[4 * c + 3];
            acc += e0 * e0 + e1 * e1 + e2 * e2 + e3 * e3;
        }
        d2[j] = acc;
    }
    __syncthreads();

    // Gather pos-set distances (j in x[i], j != i): at most K entries.
    for (int j = t; j < NN; j += 256) {
        if (j != i && ((mask[j >> 5] >> (j & 31)) & 1u)) {
            int p = atomicAdd(&pcnt, 1);
            posd[p] = d2[j];
        }
    }
    __syncthreads();

    const int P = pcnt;
    float acc = 0.f;

    // Triplet hinge: sum over k in neg-set, j in pos-set of
    // relu(d2[j] - d2[k] + alpha).
    for (int k = t; k < NN; k += 256) {
        if (k != i && !((mask[k >> 5] >> (k & 31)) & 1u)) {
            float dk = d2[k];
            for (int p = 0; p < P; ++p) {
                acc += fmaxf(posd[p] - dk + ALPHA, 0.f);
            }
        }
    }

    // Fused hierarchical consistency term for row i (threads 0..127 cover D).
    if (t < DD) {
        size_t idx = (size_t)i * DD + t;
        float w = wid[idx], kk = ken[idx], l = lrg[idx], s = sml[idx], y = yi[t];
        float a = w - kk, b = w - l, c = l - s, e = s - y;
        acc += a * a + b * b + c * c + e * e;
    }

    // Block reduction: shuffle within each 64-lane wave, then LDS across 4 waves.
    for (int off = 32; off; off >>= 1) acc += __shfl_down(acc, off, 64);
    if ((t & 63) == 0) wsum[t >> 6] = acc;
    __syncthreads();
    if (t == 0) {
        partial[i] = wsum[0] + wsum[1] + wsum[2] + wsum[3];
    }
}

// Single block: reduce the 512 per-anchor partials into out[0].
__global__ __launch_bounds__(512) void reduce_kernel(
    const float* __restrict__ partial, float* __restrict__ out)
{
    __shared__ float wsum[8];
    const int t = threadIdx.x;
    float acc = partial[t];
    for (int off = 32; off; off >>= 1) acc += __shfl_down(acc, off, 64);
    if ((t & 63) == 0) wsum[t >> 6] = acc;
    __syncthreads();
    if (t == 0) {
        float s = 0.f;
#pragma unroll
        for (int w = 0; w < 8; ++w) s += wsum[w];
        out[0] = s;
    }
}

extern "C" void kernel_launch(void* const* d_in, const int* in_sizes, int n_in,
                              void* d_out, int out_size, void* d_ws, size_t ws_size,
                              hipStream_t stream) {
    const float* wid = (const float*)d_in[0];
    const float* ken = (const float*)d_in[1];
    const float* lrg = (const float*)d_in[2];
    const float* sml = (const float*)d_in[3];
    const float* yad = (const float*)d_in[4];
    const int*   x   = (const int*)d_in[5];
    float* out     = (float*)d_out;
    float* partial = (float*)d_ws;   // 512 floats, each slot written exactly once

    area_loss_kernel<<<NN, 256, 0, stream>>>(wid, ken, lrg, sml, yad, x, partial);
    reduce_kernel<<<1, NN, 0, stream>>>(partial, out);
}

// Round 3
// 77.790 us; speedup vs baseline: 1.1098x; 1.0566x over previous
//
#include <hip/hip_runtime.h>

// Problem constants (fixed by setup_inputs): N=512 anchors, D=128 dims, K=16.
constexpr int NN = 512;
constexpr int DD = 128;
constexpr int KK = 16;
constexpr int GG = 2;           // anchors per block (halves per-block yad L2 traffic per anchor)
constexpr int NB = NN / GG;     // 256 blocks -> one per CU, all guaranteed co-resident
constexpr int NT = 512;         // 8 waves per block
#define ALPHA 0.1f
#define MAGIC 0x5CA1AB1Eu       // != 0xAAAAAAAA harness poison, != 0 (fresh alloc)

// Fully fused: per-block partial losses + flag-based completion; block 0
// performs the final reduction (no second kernel launch, no global atomics).
__global__ __launch_bounds__(NT) void area_loss_fused(
    const float* __restrict__ wid,
    const float* __restrict__ ken,
    const float* __restrict__ lrg,
    const float* __restrict__ sml,
    const float* __restrict__ yad,
    const int*   __restrict__ x,
    float*       __restrict__ out,
    float*       __restrict__ partial,   // d_ws
    unsigned*    __restrict__ flags)     // d_ws + NB floats
{
    __shared__ float    yi[GG][DD];        // the block's 2 anchor rows
    __shared__ float    d2[GG][NN];        // distances anchor->all j
    __shared__ unsigned mask[GG][NN / 32]; // membership bitsets
    __shared__ int      xl[GG][KK];        // staged x rows
    __shared__ float    posd[GG][KK];
    __shared__ int      pcnt[GG];
    __shared__ float    wsum[NT / 64];

    const int b = blockIdx.x;
    const int t = threadIdx.x;
    const int ibase = b * GG;

    // Stage anchors, x rows; init masks/counters.
    if (t < GG * DD)      ((float*)yi)[t]   = yad[(size_t)ibase * DD + t];
    if (t < GG * NN / 32) ((unsigned*)mask)[t] = 0u;
    if (t < GG * KK)      ((int*)xl)[t]     = x[ibase * KK + t];
    if (t < GG)           pcnt[t] = 0;
    __syncthreads();

    // Membership bitmasks (duplicates collapse, matching reference scatter).
    if (t < GG * KK) {
        int a = t / KK;
        int j = xl[a][t % KK];
        atomicOr(&mask[a][j >> 5], 1u << (j & 31));
    }

    // Distances: thread t owns row j=t; one yad-row read serves BOTH anchors.
    {
        const float4* row = (const float4*)(yad + (size_t)t * DD);
        float a0 = 0.f, a1 = 0.f;
#pragma unroll
        for (int c = 0; c < DD / 4; ++c) {
            float4 v = row[c];
            float e;
            e = v.x - yi[0][4 * c + 0]; a0 += e * e;
            e = v.y - yi[0][4 * c + 1]; a0 += e * e;
            e = v.z - yi[0][4 * c + 2]; a0 += e * e;
            e = v.w - yi[0][4 * c + 3]; a0 += e * e;
            e = v.x - yi[1][4 * c + 0]; a1 += e * e;
            e = v.y - yi[1][4 * c + 1]; a1 += e * e;
            e = v.z - yi[1][4 * c + 2]; a1 += e * e;
            e = v.w - yi[1][4 * c + 3]; a1 += e * e;
        }
        d2[0][t] = a0;
        d2[1][t] = a1;
    }
    __syncthreads();

    // Pos-set gather: first occurrence only (dedup), j != anchor.
    if (t < GG * KK) {
        int a = t / KK, e = t % KK;
        int j = xl[a][e];
        bool ok = (j != ibase + a);
        for (int q = 0; q < e && ok; ++q)
            if (xl[a][q] == j) ok = false;
        if (ok) {
            int p = atomicAdd(&pcnt[a], 1);
            posd[a][p] = d2[a][j];
        }
    }
    __syncthreads();

    float acc = 0.f;

    // Triplet hinge: thread t owns neg-candidate k=t for each anchor.
#pragma unroll
    for (int a = 0; a < GG; ++a) {
        const int ia = ibase + a;
        const int P  = pcnt[a];
        if (t != ia && !((mask[a][t >> 5] >> (t & 31)) & 1u)) {
            float dk = d2[a][t];
            for (int p = 0; p < P; ++p)
                acc += fmaxf(posd[a][p] - dk + ALPHA, 0.f);
        }
    }

    // Hierarchical term: this block's GG rows = contiguous slice [ibase*DD, +GG*DD).
    if (t < GG * DD) {
        size_t idx = (size_t)ibase * DD + t;
        float w = wid[idx], kk = ken[idx], l = lrg[idx], s = sml[idx];
        float y = ((float*)yi)[t];
        float p0 = w - kk, p1 = w - l, p2 = l - s, p3 = s - y;
        acc += p0 * p0 + p1 * p1 + p2 * p2 + p3 * p3;
    }

    // Block reduction: shuffle within wave-64, LDS across 8 waves.
    for (int off = 32; off; off >>= 1) acc += __shfl_down(acc, off, 64);
    if ((t & 63) == 0) wsum[t >> 6] = acc;
    __syncthreads();

    if (b != 0) {
        if (t == 0) {
            float s = 0.f;
#pragma unroll
            for (int w = 0; w < NT / 64; ++w) s += wsum[w];
            partial[b] = s;
            // Release: partial[b] visible device-wide before flag flips.
            __hip_atomic_store(&flags[b], MAGIC, __ATOMIC_RELEASE,
                               __HIP_MEMORY_SCOPE_AGENT);
        }
    } else {
        // Block 0: own sum, then gather the other 255 partials via flag spin.
        float mine = 0.f;
        if (t == 0) {
#pragma unroll
            for (int w = 0; w < NT / 64; ++w) mine += wsum[w];
        }
        __syncthreads();  // t0 done reading wsum before it's reused below

        float other = 0.f;
        if (t >= 1 && t < NB) {
            while (__hip_atomic_load(&flags[t], __ATOMIC_ACQUIRE,
                                     __HIP_MEMORY_SCOPE_AGENT) != MAGIC) {
                __builtin_amdgcn_s_sleep(1);
            }
            other = partial[t];
        }
        float tot = mine + other;
        for (int off = 32; off; off >>= 1) tot += __shfl_down(tot, off, 64);
        if ((t & 63) == 0) wsum[t >> 6] = tot;
        __syncthreads();
        if (t == 0) {
            float s = 0.f;
#pragma unroll
            for (int w = 0; w < NT / 64; ++w) s += wsum[w];
            out[0] = s;
        }
    }
}

extern "C" void kernel_launch(void* const* d_in, const int* in_sizes, int n_in,
                              void* d_out, int out_size, void* d_ws, size_t ws_size,
                              hipStream_t stream) {
    const float* wid = (const float*)d_in[0];
    const float* ken = (const float*)d_in[1];
    const float* lrg = (const float*)d_in[2];
    const float* sml = (const float*)d_in[3];
    const float* yad = (const float*)d_in[4];
    const int*   x   = (const int*)d_in[5];
    float*    out     = (float*)d_out;
    float*    partial = (float*)d_ws;              // NB floats
    unsigned* flags   = (unsigned*)(partial + NB); // NB words; poison 0xAA.. != MAGIC

    area_loss_fused<<<NB, NT, 0, stream>>>(wid, ken, lrg, sml, yad, x,
                                           out, partial, flags);
}